// Round 7
// baseline (30.187 us; speedup 1.0000x reference)
//
#include <hip/hip_runtime.h>
#include <math.h>

#define EPSF 1e-7f
#define NP 4096

typedef __attribute__((ext_vector_type(8)))  short  short8;
typedef __attribute__((ext_vector_type(8)))  __bf16 bf16x8;
typedef __attribute__((ext_vector_type(16))) float  f32x16;

__device__ __forceinline__ unsigned short bf16_rn(float x) {
    unsigned int u = __float_as_uint(x);
    unsigned int r = u + 0x7FFFu + ((u >> 16) & 1u);
    return (unsigned short)(r >> 16);
}
__device__ __forceinline__ float bf16_to_f(unsigned short h) {
    return __uint_as_float(((unsigned int)h) << 16);
}

// element-wise vector min accumulate: 16 independent v_min_f32 (no serial chain)
__device__ __forceinline__ void vmin16(f32x16& acc, const f32x16& d) {
#pragma unroll
    for (int i = 0; i < 16; ++i) acc[i] = fminf(acc[i], d[i]);
}
// fold a f32x16 to scalar min (done ONCE after the loop)
__device__ __forceinline__ float fold_scalar(const f32x16& a) {
    float m0 = fminf(fminf(a[0], a[1]),  fminf(a[2], a[3]));
    float m1 = fminf(fminf(a[4], a[5]),  fminf(a[6], a[7]));
    float m2 = fminf(fminf(a[8], a[9]),  fminf(a[10], a[11]));
    float m3 = fminf(fminf(a[12], a[13]), fminf(a[14], a[15]));
    return fminf(fminf(m0, m1), fminf(m2, m3));
}

// query-side (B operand) fragment (verified rounds 4-6, absmax 0.0):
// kg=0 -> [-2xh,-2yh,-2zh,-2xl,-2yl,-2zl,-2xh,-2yh] ; kg=1 -> [-2zh,1,1,0..]
__device__ __forceinline__ bf16x8 make_qfrag(float x, float y, float z, int kg) {
    float m2x = -2.f * x, m2y = -2.f * y, m2z = -2.f * z;
    unsigned short xh = bf16_rn(m2x), yh = bf16_rn(m2y), zh = bf16_rn(m2z);
    unsigned short xl = bf16_rn(m2x - bf16_to_f(xh));
    unsigned short yl = bf16_rn(m2y - bf16_to_f(yh));
    unsigned short zl = bf16_rn(m2z - bf16_to_f(zh));
    short8 s;
    if (kg == 0)
        s = short8{(short)xh,(short)yh,(short)zh,(short)xl,(short)yl,(short)zl,(short)xh,(short)yh};
    else
        s = short8{(short)zh,(short)0x3F80,(short)0x3F80,0,0,0,0,0};
    return __builtin_bit_cast(bf16x8, s);
}

// ---------------------------------------------------------------------------
// Chamfer stage 1: grid (16 strips, 16 combos, 4 quarters) = 1024 blocks
// (4 blocks/CU -> 4 waves/SIMD), 256 threads, 32KB LDS quarter-panel.
// Block: build 1024-pt quarter panel (split-bf16 A-frag layout, 4 pts/thr),
// then each wave crosses its 64 queries (2 B-frags) with 32 tiles:
// ds_read_b128 (prefetched) + 2 MFMA + 2x16 independent v_min_f32.
// Writes per-(query,quarter) min (+|q|^2) to ws[combo*4096+q][quarter].
// ---------------------------------------------------------------------------
__global__ __launch_bounds__(256, 4) void chamfer_q(
    const float* __restrict__ pred, const float* __restrict__ targ,
    float* __restrict__ ws)
{
    const int tid  = threadIdx.x;
    const int lane = tid & 63, w = tid >> 6, kg = lane >> 5;
    const int strip   = blockIdx.x;        // 0..15 : 256-query strip
    const int combo   = blockIdx.y;        // 0..15 : dir*8 + b
    const int quarter = blockIdx.z;        // 0..3  : 1024-pt db quarter
    const int dir = combo >> 3, b = combo & 7;

    __shared__ char panel[32768];          // 1024 pts x 32B (32 tiles x 1KB)

    // ---- query (B operand) fragments + fp32 norms
    const float* Q = (dir ? targ : pred) + (size_t)b * NP * 3;
    const int qA = strip * 256 + w * 64 + (lane & 31);
    const int qB = qA + 32;
    const float ax = Q[qA * 3], ay = Q[qA * 3 + 1], az = Q[qA * 3 + 2];
    const float bx = Q[qB * 3], by = Q[qB * 3 + 1], bz = Q[qB * 3 + 2];
    const bf16x8 fragA = make_qfrag(ax, ay, az, kg);
    const bf16x8 fragB = make_qfrag(bx, by, bz, kg);
    const float n1A = fmaf(ax, ax, fmaf(ay, ay, az * az));
    const float n1B = fmaf(bx, bx, fmaf(by, by, bz * bz));

    // ---- build 1024-pt quarter panel in LDS (4 pts/thread)
    const float* D = (dir ? pred : targ) + ((size_t)b * NP + quarter * 1024) * 3;
#pragma unroll
    for (int i = 0; i < 4; ++i) {
        const int pt = i * 256 + tid;      // local 0..1023
        const float* dp = D + (size_t)pt * 3;
        float x = dp[0], y = dp[1], z = dp[2];
        float n2 = fmaf(x, x, fmaf(y, y, z * z));
        unsigned short xh = bf16_rn(x), yh = bf16_rn(y), zh = bf16_rn(z);
        unsigned short xl = bf16_rn(x - bf16_to_f(xh));
        unsigned short yl = bf16_rn(y - bf16_to_f(yh));
        unsigned short zl = bf16_rn(z - bf16_to_f(zh));
        unsigned short nh = bf16_rn(n2);
        unsigned short nl = bf16_rn(n2 - bf16_to_f(nh));
        short8 k0 = short8{(short)xh,(short)yh,(short)zh,
                           (short)xh,(short)yh,(short)zh,
                           (short)xl,(short)yl};
        short8 k1 = short8{(short)zl,(short)nh,(short)nl,0,0,0,0,0};
        char* base = panel + (pt >> 5) * 1024 + (pt & 31) * 16;
        *(short8*)base         = k0;
        *(short8*)(base + 512) = k1;
    }
    __syncthreads();

    // ---- 32 MFMA tiles, element-wise vector-min accumulation
    f32x16 accA, accB;
#pragma unroll
    for (int i = 0; i < 16; ++i) { accA[i] = 3.4e38f; accB[i] = 3.4e38f; }
    const f32x16 zero = {0.f};
    const char* abase = panel + kg * 512 + (lane & 31) * 16;

    bf16x8 af = *(const bf16x8*)abase;
#pragma unroll 4
    for (int t = 0; t < 31; ++t) {
        bf16x8 afn = *(const bf16x8*)(abase + (t + 1) * 1024);
        f32x16 d0 = __builtin_amdgcn_mfma_f32_32x32x16_bf16(af, fragA, zero, 0, 0, 0);
        f32x16 d1 = __builtin_amdgcn_mfma_f32_32x32x16_bf16(af, fragB, zero, 0, 0, 0);
        vmin16(accA, d0);
        vmin16(accB, d1);
        af = afn;
    }
    {
        f32x16 d0 = __builtin_amdgcn_mfma_f32_32x32x16_bf16(af, fragA, zero, 0, 0, 0);
        f32x16 d1 = __builtin_amdgcn_mfma_f32_32x32x16_bf16(af, fragB, zero, 0, 0, 0);
        vmin16(accA, d0);
        vmin16(accB, d1);
    }

    // ---- fold to scalar, merge C-row halves across lane^32, add |q|^2
    float rA = fold_scalar(accA);  rA = fminf(rA, __shfl_xor(rA, 32));
    float rB = fold_scalar(accB);  rB = fminf(rB, __shfl_xor(rB, 32));
    float val = (lane < 32) ? (rA + n1A) : (rB + n1B);
    const int q = strip * 256 + w * 64 + lane;   // lane<32 -> qA, lane>=32 -> qB
    ws[(size_t)((combo << 12) + q) * 4 + quarter] = val;
}

// ---------------------------------------------------------------------------
// Stage 2: min over the 4 quarters (one float4/query), sqrt, block-sum.
// 256 blocks x 256 threads -> parts[256].
// ---------------------------------------------------------------------------
__global__ __launch_bounds__(256) void reduce_q(
    const float* __restrict__ ws, float* __restrict__ parts)
{
    const int tid = threadIdx.x;
    const int g = blockIdx.x * 256 + tid;        // combo*4096 + q
    float4 v = ((const float4*)ws)[g];
    float m = fminf(fminf(v.x, v.y), fminf(v.z, v.w));
    float dist = sqrtf(fmaxf(m, 1e-12f));
    for (int off = 32; off; off >>= 1) dist += __shfl_xor(dist, off);
    __shared__ float red[4];
    if ((tid & 63) == 0) red[tid >> 6] = dist;
    __syncthreads();
    if (tid == 0) parts[blockIdx.x] = red[0] + red[1] + red[2] + red[3];
}

// ---------------------------------------------------------------------------
// Finalize: sum 256 chamfer partials + BCE + CR -> scalar.
// ---------------------------------------------------------------------------
__global__ __launch_bounds__(256) void finalize_kernel(
    const float* __restrict__ parts,
    const float* __restrict__ prob_pred, const float* __restrict__ prob_target,
    const float* __restrict__ mu, const float* __restrict__ lb,
    const float* __restrict__ ub,
    float* __restrict__ out, int nprob, int K)
{
    const int tid = threadIdx.x;

    float bce = 0.f;
    const float pmax = 1.0f - EPSF;
    for (int i = tid; i < nprob; i += 256) {
        float p = prob_pred[i];
        p = fminf(fmaxf(p, EPSF), pmax);
        float t = prob_target[i];
        bce += t * logf(p) + (1.0f - t) * log1pf(-p);
    }

    float cr = 0.f;
    const float invK = 1.0f / (float)K;
    for (int i = tid; i < K; i += 256) {
        float c = fabsf(mu[i]) - 0.5f * (lb[i] + ub[i]) + invK;
        cr += fmaxf(c, 0.f);
    }

    float v1 = parts[tid] + cr;
    float v2 = bce;
    for (int off = 32; off; off >>= 1) {
        v1 += __shfl_xor(v1, off);
        v2 += __shfl_xor(v2, off);
    }
    __shared__ float s1[4], s2[4];
    if ((tid & 63) == 0) { s1[tid >> 6] = v1; s2[tid >> 6] = v2; }
    __syncthreads();
    if (tid == 0) {
        float V1 = s1[0] + s1[1] + s1[2] + s1[3];
        float V2 = s2[0] + s2[1] + s2[2] + s2[3];
        out[0] = V1 - V2 / (float)nprob;
    }
}

extern "C" void kernel_launch(void* const* d_in, const int* in_sizes, int n_in,
                              void* d_out, int out_size, void* d_ws, size_t ws_size,
                              hipStream_t stream) {
    const float* prob_pred   = (const float*)d_in[0];
    const float* prob_target = (const float*)d_in[1];
    const float* x_pred      = (const float*)d_in[2];
    const float* x_target    = (const float*)d_in[3];
    const float* mu          = (const float*)d_in[4];
    const float* lb          = (const float*)d_in[5];
    const float* ub          = (const float*)d_in[6];
    float* out   = (float*)d_out;
    float* ws    = (float*)d_ws;               // 65536*4 floats = 1 MB
    float* parts = ws + 65536 * 4;             // 256 floats

    const int K     = in_sizes[4];             // 1000
    const int nprob = in_sizes[0];             // 8000

    dim3 grid(16, 16, 4);
    chamfer_q<<<grid, 256, 0, stream>>>(x_pred, x_target, ws);
    reduce_q<<<256, 256, 0, stream>>>(ws, parts);
    finalize_kernel<<<1, 256, 0, stream>>>(parts, prob_pred, prob_target,
                                           mu, lb, ub, out, nprob, K);
}